// Round 11
// baseline (295.285 us; speedup 1.0000x reference)
//
#include <hip/hip_runtime.h>

// B=16, C=256, O=256, H=W=64, T_DIM=512, E=4, K=3
typedef __bf16 bf16x8 __attribute__((ext_vector_type(8)));
typedef float f32x4 __attribute__((ext_vector_type(4)));

__device__ __forceinline__ unsigned short f2bf(float f) {
  union { float f; unsigned int u; } v;
  v.f = f;
  unsigned int r = v.u + 0x7FFFu + ((v.u >> 16) & 1u);  // RNE
  return (unsigned short)(r >> 16);
}

__device__ __forceinline__ void load_lds16(const void* g, void* l) {
  __builtin_amdgcn_global_load_lds(
      (__attribute__((address_space(1))) void*)(void*)g,
      (__attribute__((address_space(3))) void*)l, 16, 0, 0);
}

// ---------- transpose + pad + pooled partials (round-5, best measured) ----------
__global__ void transpose_kernel(const float* __restrict__ x, unsigned short* __restrict__ xTpad,
                                 float* __restrict__ part) {
  int bid = blockIdx.x;
  int b = bid / 66, hp = bid % 66;
  unsigned short* rowbase = xTpad + ((size_t)(b * 66 + hp)) * 66 * 256;
  int t = threadIdx.x;
  if (hp == 0 || hp == 65) {
    uint4 z = make_uint4(0u, 0u, 0u, 0u);
    for (int i = t; i < 2112; i += 256) ((uint4*)rowbase)[i] = z;
    return;
  }
  int h = hp - 1;
  __shared__ unsigned short lds[64][264];
  __shared__ float psum[256];
  const float* xb = x + ((size_t)b * 256 * 64 + h) * 64;
  int lane = t & 63;
  #pragma unroll
  for (int g = 0; g < 16; ++g) {
    int c = g * 16 + (t >> 4);
    int w0 = (t & 15) * 4;
    float4 v = *(const float4*)&xb[(size_t)c * 4096 + w0];
    lds[w0 + 0][c] = f2bf(v.x);
    lds[w0 + 1][c] = f2bf(v.y);
    lds[w0 + 2][c] = f2bf(v.z);
    lds[w0 + 3][c] = f2bf(v.w);
    float s = v.x + v.y + v.z + v.w;
    s += __shfl_xor(s, 1); s += __shfl_xor(s, 2);
    s += __shfl_xor(s, 4); s += __shfl_xor(s, 8);
    if ((lane & 15) == 0) psum[c] = s;
  }
  __syncthreads();
  #pragma unroll
  for (int p = 0; p < 8; ++p) {
    int w = p * 8 + (t >> 5);
    int seg = t & 31;
    uint4 u = *(const uint4*)&lds[w][seg * 8];
    *(uint4*)&rowbase[(w + 1) * 256 + seg * 8] = u;
  }
  if (t < 64) {
    uint4 z = make_uint4(0u, 0u, 0u, 0u);
    int row = (t >> 5) ? 65 : 0;
    *(uint4*)&rowbase[row * 256 + (t & 31) * 8] = z;
  }
  if (t < 256) part[((size_t)b * 64 + h) * 256 + t] = psum[t];
}

// ---------- router (fp32 exact), 512 threads ----------
__global__ void router_kernel(
    const float* __restrict__ time_emb, const float* __restrict__ part,
    const float* __restrict__ Wq, const float* __restrict__ bq,
    const float* __restrict__ Wk, const float* __restrict__ bk,
    const float* __restrict__ Wv, const float* __restrict__ bv,
    const float* __restrict__ Wm1, const float* __restrict__ bm1,
    const float* __restrict__ Wm2, const float* __restrict__ bm2,
    const float* __restrict__ Wc, const float* __restrict__ bc,
    const float* __restrict__ expert_b,
    float* __restrict__ rw_out, float* __restrict__ beff_out) {
  int b = blockIdx.x, tid = threadIdx.x;
  int t = tid & 255;
  __shared__ float te[512], pl[256], qs[256], xa[256], m1s[64], xms[256], rws[4];
  te[tid] = time_emb[b * 512 + tid];
  if (tid < 256) {
    // 8 independent accumulators -> 8 outstanding loads (latency-pipelined)
    const float* pp = part + (size_t)b * 16384 + tid;
    float s0 = 0.f, s1 = 0.f, s2 = 0.f, s3 = 0.f,
          s4 = 0.f, s5 = 0.f, s6 = 0.f, s7 = 0.f;
    #pragma unroll
    for (int hh = 0; hh < 64; hh += 8) {
      s0 += pp[(hh + 0) * 256]; s1 += pp[(hh + 1) * 256];
      s2 += pp[(hh + 2) * 256]; s3 += pp[(hh + 3) * 256];
      s4 += pp[(hh + 4) * 256]; s5 += pp[(hh + 5) * 256];
      s6 += pp[(hh + 6) * 256]; s7 += pp[(hh + 7) * 256];
    }
    pl[tid] = (((s0 + s1) + (s2 + s3)) + ((s4 + s5) + (s6 + s7))) * (1.0f / 4096.0f);
  }
  __syncthreads();
  if (tid < 256) {
    float q = bq[t];
    const float4* wq4 = (const float4*)(Wq + (size_t)t * 512);
    #pragma unroll 4
    for (int i = 0; i < 128; ++i) {
      float4 w4 = wq4[i];
      q += w4.x * te[i*4] + w4.y * te[i*4+1] + w4.z * te[i*4+2] + w4.w * te[i*4+3];
    }
    qs[t] = q;
  } else {
    float k = bk[t], v = bv[t];
    const float4* wk4 = (const float4*)(Wk + (size_t)t * 256);
    const float4* wv4 = (const float4*)(Wv + (size_t)t * 256);
    #pragma unroll 4
    for (int i = 0; i < 64; ++i) {
      float4 a4 = wk4[i], b4 = wv4[i];
      float p0 = pl[i*4], p1 = pl[i*4+1], p2 = pl[i*4+2], p3 = pl[i*4+3];
      k += a4.x * p0 + a4.y * p1 + a4.z * p2 + a4.w * p3;
      v += b4.x * p0 + b4.y * p1 + b4.z * p2 + b4.w * p3;
    }
    xa[t] = k;
    xms[t] = v;
  }
  __syncthreads();
  if (tid < 256) {
    float k = xa[t], v = xms[t];
    float attn = 1.0f / (1.0f + expf(-(qs[t] * k)));
    qs[t] = v * attn;
  }
  __syncthreads();
  if (tid < 64) {
    float s = bm1[tid];
    const float4* w1 = (const float4*)(Wm1 + (size_t)tid * 256);
    #pragma unroll 4
    for (int i = 0; i < 64; ++i) {
      float4 w4 = w1[i];
      s += w4.x * qs[i*4] + w4.y * qs[i*4+1] + w4.z * qs[i*4+2] + w4.w * qs[i*4+3];
    }
    m1s[tid] = 0.5f * s * (1.0f + erff(s * 0.7071067811865476f));
  }
  __syncthreads();
  if (tid < 256) {
    float hsum = bm2[t];
    const float* w2 = Wm2 + (size_t)t * 64;
    for (int j = 0; j < 64; ++j) hsum += m1s[j] * w2[j];
    xms[t] = qs[t] + hsum;
  }
  __syncthreads();
  if (tid < 4) {
    float s = bc[tid];
    const float* wc = Wc + (size_t)tid * 256;
    for (int i = 0; i < 256; ++i) s += xms[i] * wc[i];
    float r = tanhf(s);
    rws[tid] = r;
    rw_out[b * 4 + tid] = r;
  }
  __syncthreads();
  if (tid < 256) {
    float be = 0.f;
    #pragma unroll
    for (int e = 0; e < 4; ++e) be += rws[e] * expert_b[e * 256 + t];
    beff_out[b * 256 + t] = be;
  }
}

// ---------- expert mix -> wmixT[b][ob][kc][o&15][k&7], obuf padded (conflict-free) ----------
__global__ __launch_bounds__(256, 1) void wmixT_kernel(
    const float* __restrict__ ew, const float* __restrict__ rw,
    unsigned short* __restrict__ wmixT) {
  int b = blockIdx.x >> 4, ob = blockIdx.x & 15;
  int t = threadIdx.x;
  __shared__ float lew[4][2304];                 // 36.9 KB
  __shared__ unsigned short obuf[288 * 136];     // 76.5 KB, row stride 136 (banks 0..31 2-way)
  float r0 = rw[b * 4 + 0], r1 = rw[b * 4 + 1], r2 = rw[b * 4 + 2], r3 = rw[b * 4 + 3];
  for (int op = 0; op < 16; ++op) {
    int o = ob * 16 + op;
    if (op) __syncthreads();
    #pragma unroll
    for (int e = 0; e < 4; ++e) {
      const float* s = ew + ((size_t)e * 256 + o) * 2304;
      #pragma unroll
      for (int j = 0; j < 9; ++j) lew[e][j * 256 + t] = s[j * 256 + t];
    }
    __syncthreads();
    int base = (t >> 3) * 136 + op * 8 + (t & 7);
    #pragma unroll
    for (int tt = 0; tt < 9; ++tt) {
      float m = r0 * lew[0][t * 9 + tt] + r1 * lew[1][t * 9 + tt] +
                r2 * lew[2][t * 9 + tt] + r3 * lew[3][t * 9 + tt];
      obuf[tt * 4352 + base] = f2bf(m);
    }
  }
  __syncthreads();
  unsigned short* dst = wmixT + (size_t)(b * 16 + ob) * 36864;
  #pragma unroll
  for (int i = 0; i < 18; ++i) {
    int flat = i * 256 + t;
    int row = flat >> 4, q = flat & 15;
    *(uint4*)&dst[flat * 8] = *(const uint4*)&obuf[row * 136 + q * 8];
  }
}

// ---------- conv: 256x256x2304 GEMM per sample, L2-traffic-minimized ----------
// A: gll dbuf in LDS (fragment-tiled, 32KB/tile, no dup). B: one 6x66x64c chunk
// per cc (reg-staged, swizzled ds_write) serves all 9 taps read-in-place.
// Fetch/tile: A 32KB + B 5.6KB = 672cy ~ MFMA 621cy.
__global__ __launch_bounds__(512, 1) void conv_kernel(
    const unsigned short* __restrict__ xT, const unsigned short* __restrict__ wmixT,
    const float* __restrict__ beff, float* __restrict__ out) {
  __shared__ unsigned short As[2][16384];   // 64 KB
  __shared__ unsigned short Ch[25344];      // 49.5 KB: [6][66][64] swizzled
  int bid = blockIdx.x;
  int b = ((bid & 7) << 1) | ((bid >> 7) & 1);   // same b -> same XCD
  int nt = (bid >> 3) & 15;
  int h0 = nt << 2;
  int tid = threadIdx.x;
  int wid = tid >> 6, lane = tid & 63;
  int lm = lane & 15, lg = lane >> 4;
  int wm = wid >> 1, wn = wid & 1;   // 4M x 2N wave grid

  const unsigned short* xTb = xT + (size_t)b * 66 * 66 * 256;
  const unsigned short* wmTb = wmixT + (size_t)b * 16 * 36864;

  // ---- A staging precompute (4 gll rounds; dest linear, src fragment-tiled) ----
  const unsigned short* srcA[4];
  #pragma unroll
  for (int r = 0; r < 4; ++r) {
    int u = r * 4096 + tid * 8;
    srcA[r] = wmTb + (size_t)(u >> 10) * 36864 + (u & 1023);
  }
  auto stageA = [&](int buf, int koff) {
    #pragma unroll
    for (int r = 0; r < 4; ++r)
      load_lds16(srcA[r] + koff * 128, &As[buf][r * 4096 + tid * 8]);
  };

  // ---- chunk precompute: flat f -> (row, w, cs); swizzled dest ----
  int csoff[7], cdoff[7];
  #pragma unroll
  for (int r = 0; r < 7; ++r) {
    int f = (r < 6) ? (r * 4096 + tid * 8) : (24576 + tid * 8);
    int row = f / 4224;
    int rem = f - row * 4224;
    int w = rem >> 6, cs = rem & 63;
    csoff[r] = ((h0 + row) * 66 + w) * 256 + cs;
    cdoff[r] = row * 4224 + (w << 6) + (cs ^ ((w & 7) << 3));
  }
  uint4 creg0, creg1, creg2, creg3, creg4, creg5, cregT;
  auto loadChunk = [&](int cc) {
    creg0 = *(const uint4*)(xTb + csoff[0] + cc * 64);
    creg1 = *(const uint4*)(xTb + csoff[1] + cc * 64);
    creg2 = *(const uint4*)(xTb + csoff[2] + cc * 64);
    creg3 = *(const uint4*)(xTb + csoff[3] + cc * 64);
    creg4 = *(const uint4*)(xTb + csoff[4] + cc * 64);
    creg5 = *(const uint4*)(xTb + csoff[5] + cc * 64);
    if (tid < 96) cregT = *(const uint4*)(xTb + csoff[6] + cc * 64);
  };
  auto writeChunk = [&]() {
    *(uint4*)&Ch[cdoff[0]] = creg0;
    *(uint4*)&Ch[cdoff[1]] = creg1;
    *(uint4*)&Ch[cdoff[2]] = creg2;
    *(uint4*)&Ch[cdoff[3]] = creg3;
    *(uint4*)&Ch[cdoff[4]] = creg4;
    *(uint4*)&Ch[cdoff[5]] = creg5;
    if (tid < 96) *(uint4*)&Ch[cdoff[6]] = cregT;
  };

  // ---- frag read offsets ----
  int aoff[4][2];
  #pragma unroll
  for (int mf = 0; mf < 4; ++mf)
    #pragma unroll
    for (int kk = 0; kk < 2; ++kk)
      aoff[mf][kk] = (wm * 4 + mf) * 1024 + (kk * 4 + lg) * 128 + lm * 8;
  int nbase[8], wv8[8];
  #pragma unroll
  for (int nf = 0; nf < 8; ++nf) {
    int n = wn * 128 + nf * 16 + lm;
    int hq = n >> 6, w = n & 63;
    nbase[nf] = hq * 4224 + w * 64;
    wv8[nf] = w;
  }

  f32x4 acc[4][8];
  #pragma unroll
  for (int mf = 0; mf < 4; ++mf)
    #pragma unroll
    for (int nf = 0; nf < 8; ++nf)
      acc[mf][nf] = (f32x4){0.f, 0.f, 0.f, 0.f};

  // prologue: chunk(cc0) + A(tile0: tap0,cc0)
  loadChunk(0);
  stageA(0, 0);
  asm volatile("s_waitcnt vmcnt(0)" ::: "memory");
  writeChunk();
  asm volatile("s_waitcnt lgkmcnt(0)" ::: "memory");
  __builtin_amdgcn_s_barrier();

  for (int cc = 0; cc < 4; ++cc) {
    #pragma unroll
    for (int tap = 0; tap < 9; ++tap) {
      const int kh = tap / 3, kw = tap % 3;
      int abuf = (cc + tap) & 1;
      bool last = (cc == 3 && tap == 8);
      // issue next-tile A staging + (tap0) next-chunk loads FIRST (vmcnt FIFO)
      if (!last) {
        int koff_next = (tap < 8) ? ((tap + 1) * 32 + cc * 8) : ((cc + 1) * 8);
        stageA(abuf ^ 1, koff_next);
      }
      if (tap == 0 && cc < 3) loadChunk(cc + 1);
      __builtin_amdgcn_sched_barrier(0);
      // ---- compute: 8 A-reads + 16 B-reads + 64 MFMA (compiler-pipelined) ----
      bf16x8 af[4][2];
      #pragma unroll
      for (int mf = 0; mf < 4; ++mf)
        #pragma unroll
        for (int kk = 0; kk < 2; ++kk)
          af[mf][kk] = *(const bf16x8*)&As[abuf][aoff[mf][kk]];
      #pragma unroll
      for (int nf = 0; nf < 8; ++nf) {
        int wp7 = (wv8[nf] + kw) & 7;
        int ba = nbase[nf] + kh * 4224 + kw * 64 + ((lg ^ wp7) << 3);
        bf16x8 b0 = *(const bf16x8*)&Ch[ba];
        bf16x8 b1 = *(const bf16x8*)&Ch[ba ^ 32];
        #pragma unroll
        for (int mf = 0; mf < 4; ++mf) {
          acc[mf][nf] = __builtin_amdgcn_mfma_f32_16x16x32_bf16(af[mf][0], b0, acc[mf][nf], 0, 0, 0);
          acc[mf][nf] = __builtin_amdgcn_mfma_f32_16x16x32_bf16(af[mf][1], b1, acc[mf][nf], 0, 0, 0);
        }
      }
      __builtin_amdgcn_sched_barrier(0);
      asm volatile("s_waitcnt vmcnt(0)" ::: "memory");
      __builtin_amdgcn_s_barrier();
      if (tap == 8 && cc < 3) {     // all waves done reading Ch(cc): swap in cc+1
        writeChunk();
        asm volatile("s_waitcnt lgkmcnt(0)" ::: "memory");
        __builtin_amdgcn_s_barrier();
      }
    }
  }

  // epilogue: D row (o) = lg*4 + reg, col (n) = lm
  #pragma unroll
  for (int mf = 0; mf < 4; ++mf) {
    int o = wm * 64 + mf * 16 + lg * 4;
    float be0 = beff[b * 256 + o + 0];
    float be1 = beff[b * 256 + o + 1];
    float be2 = beff[b * 256 + o + 2];
    float be3 = beff[b * 256 + o + 3];
    #pragma unroll
    for (int nf = 0; nf < 8; ++nf) {
      int n = wn * 128 + nf * 16 + lm;
      int hh = h0 + (n >> 6), w = n & 63;
      float* op = out + (((size_t)(b * 256 + o)) * 64 + hh) * 64 + w;
      op[0]            = acc[mf][nf][0] + be0;
      op[4096]         = acc[mf][nf][1] + be1;
      op[2 * 4096]     = acc[mf][nf][2] + be2;
      op[3 * 4096]     = acc[mf][nf][3] + be3;
    }
  }
}

extern "C" void kernel_launch(void* const* d_in, const int* in_sizes, int n_in,
                              void* d_out, int out_size, void* d_ws, size_t ws_size,
                              hipStream_t stream) {
  const float* x        = (const float*)d_in[0];
  const float* time_emb = (const float*)d_in[1];
  const float* Wq = (const float*)d_in[2];
  const float* bq = (const float*)d_in[3];
  const float* Wk = (const float*)d_in[4];
  const float* bk = (const float*)d_in[5];
  const float* Wv = (const float*)d_in[6];
  const float* bv = (const float*)d_in[7];
  const float* Wm1 = (const float*)d_in[8];
  const float* bm1 = (const float*)d_in[9];
  const float* Wm2 = (const float*)d_in[10];
  const float* bm2 = (const float*)d_in[11];
  const float* Wc = (const float*)d_in[12];
  const float* bc = (const float*)d_in[13];
  const float* expert_w = (const float*)d_in[14];
  const float* expert_b = (const float*)d_in[15];
  float* out = (float*)d_out;

  char* ws = (char*)d_ws;
  float* rw   = (float*)(ws + 0);
  float* beff = (float*)(ws + 1024);
  float* part = (float*)(ws + 20480);
  unsigned short* xTpad = (unsigned short*)(ws + 1069056);             // 35.7 MB
  unsigned short* wmixT = (unsigned short*)(ws + 1069056 + 35684352);  // 18.9 MB

  transpose_kernel<<<1056, 256, 0, stream>>>(x, xTpad, part);
  router_kernel<<<16, 512, 0, stream>>>(time_emb, part, Wq, bq, Wk, bk, Wv, bv,
                                        Wm1, bm1, Wm2, bm2, Wc, bc, expert_b, rw, beff);
  wmixT_kernel<<<256, 256, 0, stream>>>(expert_w, rw, wmixT);
  conv_kernel<<<256, 512, 0, stream>>>(xTpad, wmixT, beff, out);
}

// Round 12
// 154.277 us; speedup vs baseline: 1.9140x; 1.9140x over previous
//
#include <hip/hip_runtime.h>

// B=16, C=256, O=256, H=W=64, T_DIM=512, E=4, K=3
typedef __bf16 bf16x8 __attribute__((ext_vector_type(8)));
typedef float f32x4 __attribute__((ext_vector_type(4)));

__device__ __forceinline__ unsigned short f2bf(float f) {
  union { float f; unsigned int u; } v;
  v.f = f;
  unsigned int r = v.u + 0x7FFFu + ((v.u >> 16) & 1u);  // RNE
  return (unsigned short)(r >> 16);
}

__device__ __forceinline__ void load_lds16(const void* g, void* l) {
  __builtin_amdgcn_global_load_lds(
      (__attribute__((address_space(1))) void*)(void*)g,
      (__attribute__((address_space(3))) void*)l, 16, 0, 0);
}

// ---------- transpose + pad + pooled partials (round-5, best measured) ----------
__global__ void transpose_kernel(const float* __restrict__ x, unsigned short* __restrict__ xTpad,
                                 float* __restrict__ part) {
  int bid = blockIdx.x;
  int b = bid / 66, hp = bid % 66;
  unsigned short* rowbase = xTpad + ((size_t)(b * 66 + hp)) * 66 * 256;
  int t = threadIdx.x;
  if (hp == 0 || hp == 65) {
    uint4 z = make_uint4(0u, 0u, 0u, 0u);
    for (int i = t; i < 2112; i += 256) ((uint4*)rowbase)[i] = z;
    return;
  }
  int h = hp - 1;
  __shared__ unsigned short lds[64][264];
  __shared__ float psum[256];
  const float* xb = x + ((size_t)b * 256 * 64 + h) * 64;
  int lane = t & 63;
  #pragma unroll
  for (int g = 0; g < 16; ++g) {
    int c = g * 16 + (t >> 4);
    int w0 = (t & 15) * 4;
    float4 v = *(const float4*)&xb[(size_t)c * 4096 + w0];
    lds[w0 + 0][c] = f2bf(v.x);
    lds[w0 + 1][c] = f2bf(v.y);
    lds[w0 + 2][c] = f2bf(v.z);
    lds[w0 + 3][c] = f2bf(v.w);
    float s = v.x + v.y + v.z + v.w;
    s += __shfl_xor(s, 1); s += __shfl_xor(s, 2);
    s += __shfl_xor(s, 4); s += __shfl_xor(s, 8);
    if ((lane & 15) == 0) psum[c] = s;
  }
  __syncthreads();
  #pragma unroll
  for (int p = 0; p < 8; ++p) {
    int w = p * 8 + (t >> 5);
    int seg = t & 31;
    uint4 u = *(const uint4*)&lds[w][seg * 8];
    *(uint4*)&rowbase[(w + 1) * 256 + seg * 8] = u;
  }
  if (t < 64) {
    uint4 z = make_uint4(0u, 0u, 0u, 0u);
    int row = (t >> 5) ? 65 : 0;
    *(uint4*)&rowbase[row * 256 + (t & 31) * 8] = z;
  }
  if (t < 256) part[((size_t)b * 64 + h) * 256 + t] = psum[t];
}

// ---------- router (fp32 exact), 512 threads, pipelined pooled-reduce ----------
__global__ void router_kernel(
    const float* __restrict__ time_emb, const float* __restrict__ part,
    const float* __restrict__ Wq, const float* __restrict__ bq,
    const float* __restrict__ Wk, const float* __restrict__ bk,
    const float* __restrict__ Wv, const float* __restrict__ bv,
    const float* __restrict__ Wm1, const float* __restrict__ bm1,
    const float* __restrict__ Wm2, const float* __restrict__ bm2,
    const float* __restrict__ Wc, const float* __restrict__ bc,
    const float* __restrict__ expert_b,
    float* __restrict__ rw_out, float* __restrict__ beff_out) {
  int b = blockIdx.x, tid = threadIdx.x;
  int t = tid & 255;
  __shared__ float te[512], pl[256], qs[256], xa[256], m1s[64], xms[256], rws[4];
  te[tid] = time_emb[b * 512 + tid];
  if (tid < 256) {
    const float* pp = part + (size_t)b * 16384 + tid;
    float s0 = 0.f, s1 = 0.f, s2 = 0.f, s3 = 0.f,
          s4 = 0.f, s5 = 0.f, s6 = 0.f, s7 = 0.f;
    #pragma unroll
    for (int hh = 0; hh < 64; hh += 8) {
      s0 += pp[(hh + 0) * 256]; s1 += pp[(hh + 1) * 256];
      s2 += pp[(hh + 2) * 256]; s3 += pp[(hh + 3) * 256];
      s4 += pp[(hh + 4) * 256]; s5 += pp[(hh + 5) * 256];
      s6 += pp[(hh + 6) * 256]; s7 += pp[(hh + 7) * 256];
    }
    pl[tid] = (((s0 + s1) + (s2 + s3)) + ((s4 + s5) + (s6 + s7))) * (1.0f / 4096.0f);
  }
  __syncthreads();
  if (tid < 256) {
    float q = bq[t];
    const float4* wq4 = (const float4*)(Wq + (size_t)t * 512);
    #pragma unroll 4
    for (int i = 0; i < 128; ++i) {
      float4 w4 = wq4[i];
      q += w4.x * te[i*4] + w4.y * te[i*4+1] + w4.z * te[i*4+2] + w4.w * te[i*4+3];
    }
    qs[t] = q;
  } else {
    float k = bk[t], v = bv[t];
    const float4* wk4 = (const float4*)(Wk + (size_t)t * 256);
    const float4* wv4 = (const float4*)(Wv + (size_t)t * 256);
    #pragma unroll 4
    for (int i = 0; i < 64; ++i) {
      float4 a4 = wk4[i], b4 = wv4[i];
      float p0 = pl[i*4], p1 = pl[i*4+1], p2 = pl[i*4+2], p3 = pl[i*4+3];
      k += a4.x * p0 + a4.y * p1 + a4.z * p2 + a4.w * p3;
      v += b4.x * p0 + b4.y * p1 + b4.z * p2 + b4.w * p3;
    }
    xa[t] = k;
    xms[t] = v;
  }
  __syncthreads();
  if (tid < 256) {
    float k = xa[t], v = xms[t];
    float attn = 1.0f / (1.0f + expf(-(qs[t] * k)));
    qs[t] = v * attn;
  }
  __syncthreads();
  if (tid < 64) {
    float s = bm1[tid];
    const float4* w1 = (const float4*)(Wm1 + (size_t)tid * 256);
    #pragma unroll 4
    for (int i = 0; i < 64; ++i) {
      float4 w4 = w1[i];
      s += w4.x * qs[i*4] + w4.y * qs[i*4+1] + w4.z * qs[i*4+2] + w4.w * qs[i*4+3];
    }
    m1s[tid] = 0.5f * s * (1.0f + erff(s * 0.7071067811865476f));
  }
  __syncthreads();
  if (tid < 256) {
    float hsum = bm2[t];
    const float* w2 = Wm2 + (size_t)t * 64;
    for (int j = 0; j < 64; ++j) hsum += m1s[j] * w2[j];
    xms[t] = qs[t] + hsum;
  }
  __syncthreads();
  if (tid < 4) {
    float s = bc[tid];
    const float* wc = Wc + (size_t)tid * 256;
    for (int i = 0; i < 256; ++i) s += xms[i] * wc[i];
    float r = tanhf(s);
    rws[tid] = r;
    rw_out[b * 4 + tid] = r;
  }
  __syncthreads();
  if (tid < 256) {
    float be = 0.f;
    #pragma unroll
    for (int e = 0; e < 4; ++e) be += rws[e] * expert_b[e * 256 + t];
    beff_out[b * 256 + t] = be;
  }
}

// ---------- expert mix -> wmixT[b][ob][kc][o&15][k&7], obuf padded (conflict-free) ----------
__global__ __launch_bounds__(256, 1) void wmixT_kernel(
    const float* __restrict__ ew, const float* __restrict__ rw,
    unsigned short* __restrict__ wmixT) {
  int b = blockIdx.x >> 4, ob = blockIdx.x & 15;
  int t = threadIdx.x;
  __shared__ float lew[4][2304];                 // 36.9 KB
  __shared__ unsigned short obuf[288 * 136];     // 76.5 KB, row stride 136
  float r0 = rw[b * 4 + 0], r1 = rw[b * 4 + 1], r2 = rw[b * 4 + 2], r3 = rw[b * 4 + 3];
  for (int op = 0; op < 16; ++op) {
    int o = ob * 16 + op;
    if (op) __syncthreads();
    #pragma unroll
    for (int e = 0; e < 4; ++e) {
      const float* s = ew + ((size_t)e * 256 + o) * 2304;
      #pragma unroll
      for (int j = 0; j < 9; ++j) lew[e][j * 256 + t] = s[j * 256 + t];
    }
    __syncthreads();
    int base = (t >> 3) * 136 + op * 8 + (t & 7);
    #pragma unroll
    for (int tt = 0; tt < 9; ++tt) {
      float m = r0 * lew[0][t * 9 + tt] + r1 * lew[1][t * 9 + tt] +
                r2 * lew[2][t * 9 + tt] + r3 * lew[3][t * 9 + tt];
      obuf[tt * 4352 + base] = f2bf(m);
    }
  }
  __syncthreads();
  unsigned short* dst = wmixT + (size_t)(b * 16 + ob) * 36864;
  #pragma unroll
  for (int i = 0; i < 18; ++i) {
    int flat = i * 256 + t;
    int row = flat >> 4, q = flat & 15;
    *(uint4*)&dst[flat * 8] = *(const uint4*)&obuf[row * 136 + q * 8];
  }
}

// ---------- conv: 256x256x2304 GEMM per sample (round-7/10 verbatim, 74.4 us) ----------
__global__ __launch_bounds__(512, 2) void conv_kernel(
    const unsigned short* __restrict__ xT, const unsigned short* __restrict__ wmixT,
    const float* __restrict__ beff, float* __restrict__ out) {
  __shared__ unsigned short Bs[2][16384];
  int bid = blockIdx.x;
  int b = ((bid & 7) << 1) | ((bid >> 7) & 1);   // same b -> same XCD
  int nt = (bid >> 3) & 15;
  int h0 = nt << 2;
  int tid = threadIdx.x;
  int wid = tid >> 6, lane = tid & 63;
  int lm = lane & 15, lg = lane >> 4;
  int wm = wid >> 1, wn = wid & 1;   // 4M x 2N wave grid

  const unsigned short* xTb = xT + (size_t)b * 66 * 66 * 256;
  const unsigned short* wmA = wmixT + (size_t)(b * 16 + wm * 4) * 288 * 128 + lane * 8;

  int lr = lane >> 3;
  int slot_g = (lane & 7) ^ lr;
  int b_lane = lr * 256 + slot_g * 8;

  int sw0 = ((0 + lg) ^ (lm & 7)) * 8;
  int sw1 = ((4 + lg) ^ (lm & 7)) * 8;

  auto stB = [&](int buf, int kh, int cc, int kw, int q) {
    const unsigned short* src =
        xTb + (size_t)((h0 + q + kh) * 66 + wid * 8 + kw) * 256 + cc * 64 + b_lane;
    load_lds16(src, &Bs[buf][(q * 64 + wid * 8) * 64]);
  };

  f32x4 acc[4][8];
  #pragma unroll
  for (int mf = 0; mf < 4; ++mf)
    #pragma unroll
    for (int nf = 0; nf < 8; ++nf)
      acc[mf][nf] = (f32x4){0.f, 0.f, 0.f, 0.f};

  bf16x8 Ae[4][2], Ao[4][2];

  stB(0, 0, 0, 0, 0); stB(0, 0, 0, 0, 1); stB(0, 0, 0, 0, 2); stB(0, 0, 0, 0, 3);
  __builtin_amdgcn_sched_barrier(0);
  #pragma unroll
  for (int mf = 0; mf < 4; ++mf)
    #pragma unroll
    for (int kk = 0; kk < 2; ++kk)
      Ae[mf][kk] = *(const bf16x8*)(wmA + (size_t)(mf * 288 + kk * 4) * 128);
  asm volatile("s_waitcnt vmcnt(8)" ::: "memory");
  __builtin_amdgcn_s_barrier();

  auto tile_body = [&](int t, int buf, bf16x8 (&Acur)[4][2], bf16x8 (&Anext)[4][2])
      __attribute__((always_inline)) {
    bool st = (t < 35);
    if (st) {
      int tn = t + 1;
      int khn = tn / 12, rn = tn % 12, ccn = rn / 3, kwn = rn % 3;
      stB(buf ^ 1, khn, ccn, kwn, 0); stB(buf ^ 1, khn, ccn, kwn, 1);
      stB(buf ^ 1, khn, ccn, kwn, 2); stB(buf ^ 1, khn, ccn, kwn, 3);
      __builtin_amdgcn_sched_barrier(0);   // keep gll ahead of A-loads in vmcnt FIFO
      int kbase = (khn * 3 + kwn) * 32 + ccn * 8;
      #pragma unroll
      for (int mf = 0; mf < 4; ++mf)
        #pragma unroll
        for (int kk = 0; kk < 2; ++kk)
          Anext[mf][kk] = *(const bf16x8*)(wmA + (size_t)(mf * 288 + kbase + kk * 4) * 128);
    }
    #pragma unroll
    for (int nf = 0; nf < 8; ++nf) {
      bf16x8 b0 = *(const bf16x8*)&Bs[buf][(wn * 128 + nf * 16 + lm) * 64 + sw0];
      bf16x8 b1 = *(const bf16x8*)&Bs[buf][(wn * 128 + nf * 16 + lm) * 64 + sw1];
      #pragma unroll
      for (int mf = 0; mf < 4; ++mf) {
        acc[mf][nf] = __builtin_amdgcn_mfma_f32_16x16x32_bf16(Acur[mf][0], b0, acc[mf][nf], 0, 0, 0);
        acc[mf][nf] = __builtin_amdgcn_mfma_f32_16x16x32_bf16(Acur[mf][1], b1, acc[mf][nf], 0, 0, 0);
      }
    }
    if (st) {
      asm volatile("s_waitcnt vmcnt(8)" ::: "memory");
      __builtin_amdgcn_s_barrier();
    }
  };

  for (int i = 0; i < 18; ++i) {
    tile_body(2 * i, 0, Ae, Ao);
    tile_body(2 * i + 1, 1, Ao, Ae);
  }

  #pragma unroll
  for (int mf = 0; mf < 4; ++mf) {
    int o = wm * 64 + mf * 16 + lg * 4;
    float be0 = beff[b * 256 + o + 0];
    float be1 = beff[b * 256 + o + 1];
    float be2 = beff[b * 256 + o + 2];
    float be3 = beff[b * 256 + o + 3];
    #pragma unroll
    for (int nf = 0; nf < 8; ++nf) {
      int n = wn * 128 + nf * 16 + lm;
      int hh = h0 + (n >> 6), w = n & 63;
      float* op = out + (((size_t)(b * 256 + o)) * 64 + hh) * 64 + w;
      op[0]            = acc[mf][nf][0] + be0;
      op[4096]         = acc[mf][nf][1] + be1;
      op[2 * 4096]     = acc[mf][nf][2] + be2;
      op[3 * 4096]     = acc[mf][nf][3] + be3;
    }
  }
}

extern "C" void kernel_launch(void* const* d_in, const int* in_sizes, int n_in,
                              void* d_out, int out_size, void* d_ws, size_t ws_size,
                              hipStream_t stream) {
  const float* x        = (const float*)d_in[0];
  const float* time_emb = (const float*)d_in[1];
  const float* Wq = (const float*)d_in[2];
  const float* bq = (const float*)d_in[3];
  const float* Wk = (const float*)d_in[4];
  const float* bk = (const float*)d_in[5];
  const float* Wv = (const float*)d_in[6];
  const float* bv = (const float*)d_in[7];
  const float* Wm1 = (const float*)d_in[8];
  const float* bm1 = (const float*)d_in[9];
  const float* Wm2 = (const float*)d_in[10];
  const float* bm2 = (const float*)d_in[11];
  const float* Wc = (const float*)d_in[12];
  const float* bc = (const float*)d_in[13];
  const float* expert_w = (const float*)d_in[14];
  const float* expert_b = (const float*)d_in[15];
  float* out = (float*)d_out;

  char* ws = (char*)d_ws;
  float* rw   = (float*)(ws + 0);
  float* beff = (float*)(ws + 1024);
  float* part = (float*)(ws + 20480);
  unsigned short* xTpad = (unsigned short*)(ws + 1069056);             // 35.7 MB
  unsigned short* wmixT = (unsigned short*)(ws + 1069056 + 35684352);  // 18.9 MB

  transpose_kernel<<<1056, 256, 0, stream>>>(x, xTpad, part);
  router_kernel<<<16, 512, 0, stream>>>(time_emb, part, Wq, bq, Wk, bk, Wv, bv,
                                        Wm1, bm1, Wm2, bm2, Wc, bc, expert_b, rw, beff);
  wmixT_kernel<<<256, 256, 0, stream>>>(expert_w, rw, wmixT);
  conv_kernel<<<256, 512, 0, stream>>>(xTpad, wmixT, beff, out);
}

// Round 13
// 154.033 us; speedup vs baseline: 1.9170x; 1.0016x over previous
//
#include <hip/hip_runtime.h>

// B=16, C=256, O=256, H=W=64, T_DIM=512, E=4, K=3
typedef __bf16 bf16x8 __attribute__((ext_vector_type(8)));
typedef float f32x4 __attribute__((ext_vector_type(4)));

__device__ __forceinline__ unsigned short f2bf(float f) {
  union { float f; unsigned int u; } v;
  v.f = f;
  unsigned int r = v.u + 0x7FFFu + ((v.u >> 16) & 1u);  // RNE
  return (unsigned short)(r >> 16);
}

__device__ __forceinline__ void load_lds16(const void* g, void* l) {
  __builtin_amdgcn_global_load_lds(
      (__attribute__((address_space(1))) void*)(void*)g,
      (__attribute__((address_space(3))) void*)l, 16, 0, 0);
}

// ---------- transpose + pad + pooled partials (round-5, best measured) ----------
__global__ void transpose_kernel(const float* __restrict__ x, unsigned short* __restrict__ xTpad,
                                 float* __restrict__ part) {
  int bid = blockIdx.x;
  int b = bid / 66, hp = bid % 66;
  unsigned short* rowbase = xTpad + ((size_t)(b * 66 + hp)) * 66 * 256;
  int t = threadIdx.x;
  if (hp == 0 || hp == 65) {
    uint4 z = make_uint4(0u, 0u, 0u, 0u);
    for (int i = t; i < 2112; i += 256) ((uint4*)rowbase)[i] = z;
    return;
  }
  int h = hp - 1;
  __shared__ unsigned short lds[64][264];
  __shared__ float psum[256];
  const float* xb = x + ((size_t)b * 256 * 64 + h) * 64;
  int lane = t & 63;
  #pragma unroll
  for (int g = 0; g < 16; ++g) {
    int c = g * 16 + (t >> 4);
    int w0 = (t & 15) * 4;
    float4 v = *(const float4*)&xb[(size_t)c * 4096 + w0];
    lds[w0 + 0][c] = f2bf(v.x);
    lds[w0 + 1][c] = f2bf(v.y);
    lds[w0 + 2][c] = f2bf(v.z);
    lds[w0 + 3][c] = f2bf(v.w);
    float s = v.x + v.y + v.z + v.w;
    s += __shfl_xor(s, 1); s += __shfl_xor(s, 2);
    s += __shfl_xor(s, 4); s += __shfl_xor(s, 8);
    if ((lane & 15) == 0) psum[c] = s;
  }
  __syncthreads();
  #pragma unroll
  for (int p = 0; p < 8; ++p) {
    int w = p * 8 + (t >> 5);
    int seg = t & 31;
    uint4 u = *(const uint4*)&lds[w][seg * 8];
    *(uint4*)&rowbase[(w + 1) * 256 + seg * 8] = u;
  }
  if (t < 64) {
    uint4 z = make_uint4(0u, 0u, 0u, 0u);
    int row = (t >> 5) ? 65 : 0;
    *(uint4*)&rowbase[row * 256 + (t & 31) * 8] = z;
  }
  if (t < 256) part[((size_t)b * 64 + h) * 256 + t] = psum[t];
}

// ---------- router (fp32 exact), 512 threads, pipelined pooled-reduce ----------
__global__ void router_kernel(
    const float* __restrict__ time_emb, const float* __restrict__ part,
    const float* __restrict__ Wq, const float* __restrict__ bq,
    const float* __restrict__ Wk, const float* __restrict__ bk,
    const float* __restrict__ Wv, const float* __restrict__ bv,
    const float* __restrict__ Wm1, const float* __restrict__ bm1,
    const float* __restrict__ Wm2, const float* __restrict__ bm2,
    const float* __restrict__ Wc, const float* __restrict__ bc,
    const float* __restrict__ expert_b,
    float* __restrict__ rw_out, float* __restrict__ beff_out) {
  int b = blockIdx.x, tid = threadIdx.x;
  int t = tid & 255;
  __shared__ float te[512], pl[256], qs[256], xa[256], m1s[64], xms[256], rws[4];
  te[tid] = time_emb[b * 512 + tid];
  if (tid < 256) {
    const float* pp = part + (size_t)b * 16384 + tid;
    float s0 = 0.f, s1 = 0.f, s2 = 0.f, s3 = 0.f,
          s4 = 0.f, s5 = 0.f, s6 = 0.f, s7 = 0.f;
    #pragma unroll
    for (int hh = 0; hh < 64; hh += 8) {
      s0 += pp[(hh + 0) * 256]; s1 += pp[(hh + 1) * 256];
      s2 += pp[(hh + 2) * 256]; s3 += pp[(hh + 3) * 256];
      s4 += pp[(hh + 4) * 256]; s5 += pp[(hh + 5) * 256];
      s6 += pp[(hh + 6) * 256]; s7 += pp[(hh + 7) * 256];
    }
    pl[tid] = (((s0 + s1) + (s2 + s3)) + ((s4 + s5) + (s6 + s7))) * (1.0f / 4096.0f);
  }
  __syncthreads();
  if (tid < 256) {
    float q = bq[t];
    const float4* wq4 = (const float4*)(Wq + (size_t)t * 512);
    #pragma unroll 4
    for (int i = 0; i < 128; ++i) {
      float4 w4 = wq4[i];
      q += w4.x * te[i*4] + w4.y * te[i*4+1] + w4.z * te[i*4+2] + w4.w * te[i*4+3];
    }
    qs[t] = q;
  } else {
    float k = bk[t], v = bv[t];
    const float4* wk4 = (const float4*)(Wk + (size_t)t * 256);
    const float4* wv4 = (const float4*)(Wv + (size_t)t * 256);
    #pragma unroll 4
    for (int i = 0; i < 64; ++i) {
      float4 a4 = wk4[i], b4 = wv4[i];
      float p0 = pl[i*4], p1 = pl[i*4+1], p2 = pl[i*4+2], p3 = pl[i*4+3];
      k += a4.x * p0 + a4.y * p1 + a4.z * p2 + a4.w * p3;
      v += b4.x * p0 + b4.y * p1 + b4.z * p2 + b4.w * p3;
    }
    xa[t] = k;
    xms[t] = v;
  }
  __syncthreads();
  if (tid < 256) {
    float k = xa[t], v = xms[t];
    float attn = 1.0f / (1.0f + expf(-(qs[t] * k)));
    qs[t] = v * attn;
  }
  __syncthreads();
  if (tid < 64) {
    float s = bm1[tid];
    const float4* w1 = (const float4*)(Wm1 + (size_t)tid * 256);
    #pragma unroll 4
    for (int i = 0; i < 64; ++i) {
      float4 w4 = w1[i];
      s += w4.x * qs[i*4] + w4.y * qs[i*4+1] + w4.z * qs[i*4+2] + w4.w * qs[i*4+3];
    }
    m1s[tid] = 0.5f * s * (1.0f + erff(s * 0.7071067811865476f));
  }
  __syncthreads();
  if (tid < 256) {
    float hsum = bm2[t];
    const float* w2 = Wm2 + (size_t)t * 64;
    for (int j = 0; j < 64; ++j) hsum += m1s[j] * w2[j];
    xms[t] = qs[t] + hsum;
  }
  __syncthreads();
  if (tid < 4) {
    float s = bc[tid];
    const float* wc = Wc + (size_t)tid * 256;
    for (int i = 0; i < 256; ++i) s += xms[i] * wc[i];
    float r = tanhf(s);
    rws[tid] = r;
    rw_out[b * 4 + tid] = r;
  }
  __syncthreads();
  if (tid < 256) {
    float be = 0.f;
    #pragma unroll
    for (int e = 0; e < 4; ++e) be += rws[e] * expert_b[e * 256 + t];
    beff_out[b * 256 + t] = be;
  }
}

// ---------- expert mix -> wmixT[b][ob][kc][o&15][k&7], obuf padded (conflict-free) ----------
__global__ __launch_bounds__(256, 1) void wmixT_kernel(
    const float* __restrict__ ew, const float* __restrict__ rw,
    unsigned short* __restrict__ wmixT) {
  int b = blockIdx.x >> 4, ob = blockIdx.x & 15;
  int t = threadIdx.x;
  __shared__ float lew[4][2304];                 // 36.9 KB
  __shared__ unsigned short obuf[288 * 136];     // 76.5 KB, row stride 136
  float r0 = rw[b * 4 + 0], r1 = rw[b * 4 + 1], r2 = rw[b * 4 + 2], r3 = rw[b * 4 + 3];
  for (int op = 0; op < 16; ++op) {
    int o = ob * 16 + op;
    if (op) __syncthreads();
    #pragma unroll
    for (int e = 0; e < 4; ++e) {
      const float* s = ew + ((size_t)e * 256 + o) * 2304;
      #pragma unroll
      for (int j = 0; j < 9; ++j) lew[e][j * 256 + t] = s[j * 256 + t];
    }
    __syncthreads();
    int base = (t >> 3) * 136 + op * 8 + (t & 7);
    #pragma unroll
    for (int tt = 0; tt < 9; ++tt) {
      float m = r0 * lew[0][t * 9 + tt] + r1 * lew[1][t * 9 + tt] +
                r2 * lew[2][t * 9 + tt] + r3 * lew[3][t * 9 + tt];
      obuf[tt * 4352 + base] = f2bf(m);
    }
  }
  __syncthreads();
  unsigned short* dst = wmixT + (size_t)(b * 16 + ob) * 36864;
  #pragma unroll
  for (int i = 0; i < 18; ++i) {
    int flat = i * 256 + t;
    int row = flat >> 4, q = flat & 15;
    *(uint4*)&dst[flat * 8] = *(const uint4*)&obuf[row * 136 + q * 8];
  }
}

// ---------- conv: 256x256x2304 GEMM per sample (round-7/10 verbatim, 74.4 us) ----------
__global__ __launch_bounds__(512, 2) void conv_kernel(
    const unsigned short* __restrict__ xT, const unsigned short* __restrict__ wmixT,
    const float* __restrict__ beff, float* __restrict__ out) {
  __shared__ unsigned short Bs[2][16384];
  int bid = blockIdx.x;
  int b = ((bid & 7) << 1) | ((bid >> 7) & 1);   // same b -> same XCD
  int nt = (bid >> 3) & 15;
  int h0 = nt << 2;
  int tid = threadIdx.x;
  int wid = tid >> 6, lane = tid & 63;
  int lm = lane & 15, lg = lane >> 4;
  int wm = wid >> 1, wn = wid & 1;   // 4M x 2N wave grid

  const unsigned short* xTb = xT + (size_t)b * 66 * 66 * 256;
  const unsigned short* wmA = wmixT + (size_t)(b * 16 + wm * 4) * 288 * 128 + lane * 8;

  int lr = lane >> 3;
  int slot_g = (lane & 7) ^ lr;
  int b_lane = lr * 256 + slot_g * 8;

  int sw0 = ((0 + lg) ^ (lm & 7)) * 8;
  int sw1 = ((4 + lg) ^ (lm & 7)) * 8;

  auto stB = [&](int buf, int kh, int cc, int kw, int q) {
    const unsigned short* src =
        xTb + (size_t)((h0 + q + kh) * 66 + wid * 8 + kw) * 256 + cc * 64 + b_lane;
    load_lds16(src, &Bs[buf][(q * 64 + wid * 8) * 64]);
  };

  f32x4 acc[4][8];
  #pragma unroll
  for (int mf = 0; mf < 4; ++mf)
    #pragma unroll
    for (int nf = 0; nf < 8; ++nf)
      acc[mf][nf] = (f32x4){0.f, 0.f, 0.f, 0.f};

  bf16x8 Ae[4][2], Ao[4][2];

  stB(0, 0, 0, 0, 0); stB(0, 0, 0, 0, 1); stB(0, 0, 0, 0, 2); stB(0, 0, 0, 0, 3);
  __builtin_amdgcn_sched_barrier(0);
  #pragma unroll
  for (int mf = 0; mf < 4; ++mf)
    #pragma unroll
    for (int kk = 0; kk < 2; ++kk)
      Ae[mf][kk] = *(const bf16x8*)(wmA + (size_t)(mf * 288 + kk * 4) * 128);
  asm volatile("s_waitcnt vmcnt(8)" ::: "memory");
  __builtin_amdgcn_s_barrier();

  auto tile_body = [&](int t, int buf, bf16x8 (&Acur)[4][2], bf16x8 (&Anext)[4][2])
      __attribute__((always_inline)) {
    bool st = (t < 35);
    if (st) {
      int tn = t + 1;
      int khn = tn / 12, rn = tn % 12, ccn = rn / 3, kwn = rn % 3;
      stB(buf ^ 1, khn, ccn, kwn, 0); stB(buf ^ 1, khn, ccn, kwn, 1);
      stB(buf ^ 1, khn, ccn, kwn, 2); stB(buf ^ 1, khn, ccn, kwn, 3);
      __builtin_amdgcn_sched_barrier(0);   // keep gll ahead of A-loads in vmcnt FIFO
      int kbase = (khn * 3 + kwn) * 32 + ccn * 8;
      #pragma unroll
      for (int mf = 0; mf < 4; ++mf)
        #pragma unroll
        for (int kk = 0; kk < 2; ++kk)
          Anext[mf][kk] = *(const bf16x8*)(wmA + (size_t)(mf * 288 + kbase + kk * 4) * 128);
    }
    #pragma unroll
    for (int nf = 0; nf < 8; ++nf) {
      bf16x8 b0 = *(const bf16x8*)&Bs[buf][(wn * 128 + nf * 16 + lm) * 64 + sw0];
      bf16x8 b1 = *(const bf16x8*)&Bs[buf][(wn * 128 + nf * 16 + lm) * 64 + sw1];
      #pragma unroll
      for (int mf = 0; mf < 4; ++mf) {
        acc[mf][nf] = __builtin_amdgcn_mfma_f32_16x16x32_bf16(Acur[mf][0], b0, acc[mf][nf], 0, 0, 0);
        acc[mf][nf] = __builtin_amdgcn_mfma_f32_16x16x32_bf16(Acur[mf][1], b1, acc[mf][nf], 0, 0, 0);
      }
    }
    if (st) {
      asm volatile("s_waitcnt vmcnt(8)" ::: "memory");
      __builtin_amdgcn_s_barrier();
    }
  };

  for (int i = 0; i < 18; ++i) {
    tile_body(2 * i, 0, Ae, Ao);
    tile_body(2 * i + 1, 1, Ao, Ae);
  }

  #pragma unroll
  for (int mf = 0; mf < 4; ++mf) {
    int o = wm * 64 + mf * 16 + lg * 4;
    float be0 = beff[b * 256 + o + 0];
    float be1 = beff[b * 256 + o + 1];
    float be2 = beff[b * 256 + o + 2];
    float be3 = beff[b * 256 + o + 3];
    #pragma unroll
    for (int nf = 0; nf < 8; ++nf) {
      int n = wn * 128 + nf * 16 + lm;
      int hh = h0 + (n >> 6), w = n & 63;
      float* op = out + (((size_t)(b * 256 + o)) * 64 + hh) * 64 + w;
      op[0]            = acc[mf][nf][0] + be0;
      op[4096]         = acc[mf][nf][1] + be1;
      op[2 * 4096]     = acc[mf][nf][2] + be2;
      op[3 * 4096]     = acc[mf][nf][3] + be3;
    }
  }
}

extern "C" void kernel_launch(void* const* d_in, const int* in_sizes, int n_in,
                              void* d_out, int out_size, void* d_ws, size_t ws_size,
                              hipStream_t stream) {
  const float* x        = (const float*)d_in[0];
  const float* time_emb = (const float*)d_in[1];
  const float* Wq = (const float*)d_in[2];
  const float* bq = (const float*)d_in[3];
  const float* Wk = (const float*)d_in[4];
  const float* bk = (const float*)d_in[5];
  const float* Wv = (const float*)d_in[6];
  const float* bv = (const float*)d_in[7];
  const float* Wm1 = (const float*)d_in[8];
  const float* bm1 = (const float*)d_in[9];
  const float* Wm2 = (const float*)d_in[10];
  const float* bm2 = (const float*)d_in[11];
  const float* Wc = (const float*)d_in[12];
  const float* bc = (const float*)d_in[13];
  const float* expert_w = (const float*)d_in[14];
  const float* expert_b = (const float*)d_in[15];
  float* out = (float*)d_out;

  char* ws = (char*)d_ws;
  float* rw   = (float*)(ws + 0);
  float* beff = (float*)(ws + 1024);
  float* part = (float*)(ws + 20480);
  unsigned short* xTpad = (unsigned short*)(ws + 1069056);             // 35.7 MB
  unsigned short* wmixT = (unsigned short*)(ws + 1069056 + 35684352);  // 18.9 MB

  transpose_kernel<<<1056, 256, 0, stream>>>(x, xTpad, part);
  router_kernel<<<16, 512, 0, stream>>>(time_emb, part, Wq, bq, Wk, bk, Wv, bv,
                                        Wm1, bm1, Wm2, bm2, Wc, bc, expert_b, rw, beff);
  wmixT_kernel<<<256, 256, 0, stream>>>(expert_w, rw, wmixT);
  conv_kernel<<<256, 512, 0, stream>>>(xTpad, wmixT, beff, out);
}

// Round 14
// 148.728 us; speedup vs baseline: 1.9854x; 1.0357x over previous
//
#include <hip/hip_runtime.h>

// B=16, C=256, O=256, H=W=64, T_DIM=512, E=4, K=3
typedef __bf16 bf16x8 __attribute__((ext_vector_type(8)));
typedef float f32x4 __attribute__((ext_vector_type(4)));

__device__ __forceinline__ unsigned short f2bf(float f) {
  union { float f; unsigned int u; } v;
  v.f = f;
  unsigned int r = v.u + 0x7FFFu + ((v.u >> 16) & 1u);  // RNE
  return (unsigned short)(r >> 16);
}

__device__ __forceinline__ void load_lds16(const void* g, void* l) {
  __builtin_amdgcn_global_load_lds(
      (__attribute__((address_space(1))) void*)(void*)g,
      (__attribute__((address_space(3))) void*)l, 16, 0, 0);
}

// ---------- transpose + pad + pooled partials (R5 + write-phase XOR swizzle) ----------
__global__ void transpose_kernel(const float* __restrict__ x, unsigned short* __restrict__ xTpad,
                                 float* __restrict__ part) {
  int bid = blockIdx.x;
  int b = bid / 66, hp = bid % 66;
  unsigned short* rowbase = xTpad + ((size_t)(b * 66 + hp)) * 66 * 256;
  int t = threadIdx.x;
  if (hp == 0 || hp == 65) {
    uint4 z = make_uint4(0u, 0u, 0u, 0u);
    for (int i = t; i < 2112; i += 256) ((uint4*)rowbase)[i] = z;
    return;
  }
  int h = hp - 1;
  __shared__ unsigned short lds[64 * 264];
  __shared__ float psum[256];
  const float* xb = x + ((size_t)b * 256 * 64 + h) * 64;
  int lane = t & 63;
  int w0 = (t & 15) * 4;
  int sxw = ((t & 15) & 7) << 3;     // ((w0+j)>>2)&7)<<3, constant over j=0..3
  #pragma unroll
  for (int g = 0; g < 16; ++g) {
    int c = g * 16 + (t >> 4);
    int cx = c ^ sxw;
    float4 v = *(const float4*)&xb[(size_t)c * 4096 + w0];
    lds[(w0 + 0) * 264 + cx] = f2bf(v.x);
    lds[(w0 + 1) * 264 + cx] = f2bf(v.y);
    lds[(w0 + 2) * 264 + cx] = f2bf(v.z);
    lds[(w0 + 3) * 264 + cx] = f2bf(v.w);
    float s = v.x + v.y + v.z + v.w;
    s += __shfl_xor(s, 1); s += __shfl_xor(s, 2);
    s += __shfl_xor(s, 4); s += __shfl_xor(s, 8);
    if ((lane & 15) == 0) psum[c] = s;
  }
  __syncthreads();
  #pragma unroll
  for (int p = 0; p < 8; ++p) {
    int w = p * 8 + (t >> 5);
    int seg = t & 31;
    int sxr = ((w >> 2) & 7) << 3;
    uint4 u = *(const uint4*)&lds[w * 264 + ((seg * 8) ^ sxr)];
    *(uint4*)&rowbase[(w + 1) * 256 + seg * 8] = u;
  }
  if (t < 64) {
    uint4 z = make_uint4(0u, 0u, 0u, 0u);
    int row = (t >> 5) ? 65 : 0;
    *(uint4*)&rowbase[row * 256 + (t & 31) * 8] = z;
  }
  if (t < 256) part[((size_t)b * 64 + h) * 256 + t] = psum[t];
}

// ---------- router (fp32 exact), 512 threads, pipelined pooled-reduce ----------
__global__ void router_kernel(
    const float* __restrict__ time_emb, const float* __restrict__ part,
    const float* __restrict__ Wq, const float* __restrict__ bq,
    const float* __restrict__ Wk, const float* __restrict__ bk,
    const float* __restrict__ Wv, const float* __restrict__ bv,
    const float* __restrict__ Wm1, const float* __restrict__ bm1,
    const float* __restrict__ Wm2, const float* __restrict__ bm2,
    const float* __restrict__ Wc, const float* __restrict__ bc,
    const float* __restrict__ expert_b,
    float* __restrict__ rw_out, float* __restrict__ beff_out) {
  int b = blockIdx.x, tid = threadIdx.x;
  int t = tid & 255;
  __shared__ float te[512], pl[256], qs[256], xa[256], m1s[64], xms[256], rws[4];
  te[tid] = time_emb[b * 512 + tid];
  if (tid < 256) {
    const float* pp = part + (size_t)b * 16384 + tid;
    float s0 = 0.f, s1 = 0.f, s2 = 0.f, s3 = 0.f,
          s4 = 0.f, s5 = 0.f, s6 = 0.f, s7 = 0.f;
    #pragma unroll
    for (int hh = 0; hh < 64; hh += 8) {
      s0 += pp[(hh + 0) * 256]; s1 += pp[(hh + 1) * 256];
      s2 += pp[(hh + 2) * 256]; s3 += pp[(hh + 3) * 256];
      s4 += pp[(hh + 4) * 256]; s5 += pp[(hh + 5) * 256];
      s6 += pp[(hh + 6) * 256]; s7 += pp[(hh + 7) * 256];
    }
    pl[tid] = (((s0 + s1) + (s2 + s3)) + ((s4 + s5) + (s6 + s7))) * (1.0f / 4096.0f);
  }
  __syncthreads();
  if (tid < 256) {
    float q = bq[t];
    const float4* wq4 = (const float4*)(Wq + (size_t)t * 512);
    #pragma unroll 4
    for (int i = 0; i < 128; ++i) {
      float4 w4 = wq4[i];
      q += w4.x * te[i*4] + w4.y * te[i*4+1] + w4.z * te[i*4+2] + w4.w * te[i*4+3];
    }
    qs[t] = q;
  } else {
    float k = bk[t], v = bv[t];
    const float4* wk4 = (const float4*)(Wk + (size_t)t * 256);
    const float4* wv4 = (const float4*)(Wv + (size_t)t * 256);
    #pragma unroll 4
    for (int i = 0; i < 64; ++i) {
      float4 a4 = wk4[i], b4 = wv4[i];
      float p0 = pl[i*4], p1 = pl[i*4+1], p2 = pl[i*4+2], p3 = pl[i*4+3];
      k += a4.x * p0 + a4.y * p1 + a4.z * p2 + a4.w * p3;
      v += b4.x * p0 + b4.y * p1 + b4.z * p2 + b4.w * p3;
    }
    xa[t] = k;
    xms[t] = v;
  }
  __syncthreads();
  if (tid < 256) {
    float k = xa[t], v = xms[t];
    float attn = 1.0f / (1.0f + expf(-(qs[t] * k)));
    qs[t] = v * attn;
  }
  __syncthreads();
  if (tid < 64) {
    float s = bm1[tid];
    const float4* w1 = (const float4*)(Wm1 + (size_t)tid * 256);
    #pragma unroll 4
    for (int i = 0; i < 64; ++i) {
      float4 w4 = w1[i];
      s += w4.x * qs[i*4] + w4.y * qs[i*4+1] + w4.z * qs[i*4+2] + w4.w * qs[i*4+3];
    }
    m1s[tid] = 0.5f * s * (1.0f + erff(s * 0.7071067811865476f));
  }
  __syncthreads();
  if (tid < 256) {
    float hsum = bm2[t];
    const float* w2 = Wm2 + (size_t)t * 64;
    for (int j = 0; j < 64; ++j) hsum += m1s[j] * w2[j];
    xms[t] = qs[t] + hsum;
  }
  __syncthreads();
  if (tid < 4) {
    float s = bc[tid];
    const float* wc = Wc + (size_t)tid * 256;
    for (int i = 0; i < 256; ++i) s += xms[i] * wc[i];
    float r = tanhf(s);
    rws[tid] = r;
    rw_out[b * 4 + tid] = r;
  }
  __syncthreads();
  if (tid < 256) {
    float be = 0.f;
    #pragma unroll
    for (int e = 0; e < 4; ++e) be += rws[e] * expert_b[e * 256 + t];
    beff_out[b * 256 + t] = be;
  }
}

// ---------- expert mix -> wmixT, LDS-free / barrier-free ----------
// Thread t owns c=t; reads 4 experts x 9 contiguous taps (36B/lane, coalesced);
// stores bf16 into fragment layout (lanes 0-7 contiguous 16B groups).
__global__ void wmixT_kernel(const float* __restrict__ ew, const float* __restrict__ rw,
                             unsigned short* __restrict__ wmixT) {
  int b = blockIdx.x >> 4, ob = blockIdx.x & 15;
  int t = threadIdx.x;
  float r0 = rw[b * 4 + 0], r1 = rw[b * 4 + 1], r2 = rw[b * 4 + 2], r3 = rw[b * 4 + 3];
  unsigned short* dst = wmixT + (size_t)(b * 16 + ob) * 36864 + (t >> 3) * 128 + (t & 7);
  #pragma unroll 2
  for (int op = 0; op < 16; ++op) {
    int o = ob * 16 + op;
    const float* s0 = ew + ((size_t)(0 * 256 + o) * 256 + t) * 9;
    const float* s1 = ew + ((size_t)(1 * 256 + o) * 256 + t) * 9;
    const float* s2 = ew + ((size_t)(2 * 256 + o) * 256 + t) * 9;
    const float* s3 = ew + ((size_t)(3 * 256 + o) * 256 + t) * 9;
    #pragma unroll
    for (int tt = 0; tt < 9; ++tt) {
      float m = r0 * s0[tt] + r1 * s1[tt] + r2 * s2[tt] + r3 * s3[tt];
      dst[tt * 4096 + op * 8] = f2bf(m);   // tap stride = 32*128 elems
    }
  }
}

// ---------- conv: 256x256x2304 GEMM per sample (R7/R10/R13 verbatim, 74.4 us) ----------
__global__ __launch_bounds__(512, 2) void conv_kernel(
    const unsigned short* __restrict__ xT, const unsigned short* __restrict__ wmixT,
    const float* __restrict__ beff, float* __restrict__ out) {
  __shared__ unsigned short Bs[2][16384];
  int bid = blockIdx.x;
  int b = ((bid & 7) << 1) | ((bid >> 7) & 1);   // same b -> same XCD
  int nt = (bid >> 3) & 15;
  int h0 = nt << 2;
  int tid = threadIdx.x;
  int wid = tid >> 6, lane = tid & 63;
  int lm = lane & 15, lg = lane >> 4;
  int wm = wid >> 1, wn = wid & 1;   // 4M x 2N wave grid

  const unsigned short* xTb = xT + (size_t)b * 66 * 66 * 256;
  const unsigned short* wmA = wmixT + (size_t)(b * 16 + wm * 4) * 288 * 128 + lane * 8;

  int lr = lane >> 3;
  int slot_g = (lane & 7) ^ lr;
  int b_lane = lr * 256 + slot_g * 8;

  int sw0 = ((0 + lg) ^ (lm & 7)) * 8;
  int sw1 = ((4 + lg) ^ (lm & 7)) * 8;

  auto stB = [&](int buf, int kh, int cc, int kw, int q) {
    const unsigned short* src =
        xTb + (size_t)((h0 + q + kh) * 66 + wid * 8 + kw) * 256 + cc * 64 + b_lane;
    load_lds16(src, &Bs[buf][(q * 64 + wid * 8) * 64]);
  };

  f32x4 acc[4][8];
  #pragma unroll
  for (int mf = 0; mf < 4; ++mf)
    #pragma unroll
    for (int nf = 0; nf < 8; ++nf)
      acc[mf][nf] = (f32x4){0.f, 0.f, 0.f, 0.f};

  bf16x8 Ae[4][2], Ao[4][2];

  stB(0, 0, 0, 0, 0); stB(0, 0, 0, 0, 1); stB(0, 0, 0, 0, 2); stB(0, 0, 0, 0, 3);
  __builtin_amdgcn_sched_barrier(0);
  #pragma unroll
  for (int mf = 0; mf < 4; ++mf)
    #pragma unroll
    for (int kk = 0; kk < 2; ++kk)
      Ae[mf][kk] = *(const bf16x8*)(wmA + (size_t)(mf * 288 + kk * 4) * 128);
  asm volatile("s_waitcnt vmcnt(8)" ::: "memory");
  __builtin_amdgcn_s_barrier();

  auto tile_body = [&](int t, int buf, bf16x8 (&Acur)[4][2], bf16x8 (&Anext)[4][2])
      __attribute__((always_inline)) {
    bool st = (t < 35);
    if (st) {
      int tn = t + 1;
      int khn = tn / 12, rn = tn % 12, ccn = rn / 3, kwn = rn % 3;
      stB(buf ^ 1, khn, ccn, kwn, 0); stB(buf ^ 1, khn, ccn, kwn, 1);
      stB(buf ^ 1, khn, ccn, kwn, 2); stB(buf ^ 1, khn, ccn, kwn, 3);
      __builtin_amdgcn_sched_barrier(0);   // keep gll ahead of A-loads in vmcnt FIFO
      int kbase = (khn * 3 + kwn) * 32 + ccn * 8;
      #pragma unroll
      for (int mf = 0; mf < 4; ++mf)
        #pragma unroll
        for (int kk = 0; kk < 2; ++kk)
          Anext[mf][kk] = *(const bf16x8*)(wmA + (size_t)(mf * 288 + kbase + kk * 4) * 128);
    }
    #pragma unroll
    for (int nf = 0; nf < 8; ++nf) {
      bf16x8 b0 = *(const bf16x8*)&Bs[buf][(wn * 128 + nf * 16 + lm) * 64 + sw0];
      bf16x8 b1 = *(const bf16x8*)&Bs[buf][(wn * 128 + nf * 16 + lm) * 64 + sw1];
      #pragma unroll
      for (int mf = 0; mf < 4; ++mf) {
        acc[mf][nf] = __builtin_amdgcn_mfma_f32_16x16x32_bf16(Acur[mf][0], b0, acc[mf][nf], 0, 0, 0);
        acc[mf][nf] = __builtin_amdgcn_mfma_f32_16x16x32_bf16(Acur[mf][1], b1, acc[mf][nf], 0, 0, 0);
      }
    }
    if (st) {
      asm volatile("s_waitcnt vmcnt(8)" ::: "memory");
      __builtin_amdgcn_s_barrier();
    }
  };

  for (int i = 0; i < 18; ++i) {
    tile_body(2 * i, 0, Ae, Ao);
    tile_body(2 * i + 1, 1, Ao, Ae);
  }

  #pragma unroll
  for (int mf = 0; mf < 4; ++mf) {
    int o = wm * 64 + mf * 16 + lg * 4;
    float be0 = beff[b * 256 + o + 0];
    float be1 = beff[b * 256 + o + 1];
    float be2 = beff[b * 256 + o + 2];
    float be3 = beff[b * 256 + o + 3];
    #pragma unroll
    for (int nf = 0; nf < 8; ++nf) {
      int n = wn * 128 + nf * 16 + lm;
      int hh = h0 + (n >> 6), w = n & 63;
      float* op = out + (((size_t)(b * 256 + o)) * 64 + hh) * 64 + w;
      op[0]            = acc[mf][nf][0] + be0;
      op[4096]         = acc[mf][nf][1] + be1;
      op[2 * 4096]     = acc[mf][nf][2] + be2;
      op[3 * 4096]     = acc[mf][nf][3] + be3;
    }
  }
}

extern "C" void kernel_launch(void* const* d_in, const int* in_sizes, int n_in,
                              void* d_out, int out_size, void* d_ws, size_t ws_size,
                              hipStream_t stream) {
  const float* x        = (const float*)d_in[0];
  const float* time_emb = (const float*)d_in[1];
  const float* Wq = (const float*)d_in[2];
  const float* bq = (const float*)d_in[3];
  const float* Wk = (const float*)d_in[4];
  const float* bk = (const float*)d_in[5];
  const float* Wv = (const float*)d_in[6];
  const float* bv = (const float*)d_in[7];
  const float* Wm1 = (const float*)d_in[8];
  const float* bm1 = (const float*)d_in[9];
  const float* Wm2 = (const float*)d_in[10];
  const float* bm2 = (const float*)d_in[11];
  const float* Wc = (const float*)d_in[12];
  const float* bc = (const float*)d_in[13];
  const float* expert_w = (const float*)d_in[14];
  const float* expert_b = (const float*)d_in[15];
  float* out = (float*)d_out;

  char* ws = (char*)d_ws;
  float* rw   = (float*)(ws + 0);
  float* beff = (float*)(ws + 1024);
  float* part = (float*)(ws + 20480);
  unsigned short* xTpad = (unsigned short*)(ws + 1069056);             // 35.7 MB
  unsigned short* wmixT = (unsigned short*)(ws + 1069056 + 35684352);  // 18.9 MB

  transpose_kernel<<<1056, 256, 0, stream>>>(x, xTpad, part);
  router_kernel<<<16, 512, 0, stream>>>(time_emb, part, Wq, bq, Wk, bk, Wv, bv,
                                        Wm1, bm1, Wm2, bm2, Wc, bc, expert_b, rw, beff);
  wmixT_kernel<<<256, 256, 0, stream>>>(expert_w, rw, wmixT);
  conv_kernel<<<256, 512, 0, stream>>>(xTpad, wmixT, beff, out);
}